// Round 2
// baseline (3621.730 us; speedup 1.0000x reference)
//
#include <hip/hip_runtime.h>
#include <hip/hip_bf16.h>
#include <cstdint>

// Sizes (fixed by the problem)
#define S_LEN 512
#define B_SZ  64
#define V_IN  2000
#define H_SZ  256
#define Z_SZ  64

typedef __attribute__((ext_vector_type(4))) float  f32x4_t;
typedef __attribute__((ext_vector_type(8))) short  bf16x8_t;

// fp32 -> bf16 (RNE)
__device__ __forceinline__ ushort f2b(float f) {
    uint32_t u = __float_as_uint(f);
    u += 0x7FFFu + ((u >> 16) & 1u);
    return (ushort)(u >> 16);
}
__device__ __forceinline__ float b2f(ushort s) {
    return __uint_as_float(((uint32_t)s) << 16);
}
__device__ __forceinline__ ushort u4get(ushort4 v, int i) {
    return i == 0 ? v.x : i == 1 ? v.y : i == 2 ? v.z : v.w;
}

// =====================================================================
// K1: projection GEMM.  Gi[s][d][t][col][b] (bf16) =
//     x[s,b,:] @ Wih_d.T + bih_d (+ bhh_d folded for r,z gates)
// M = 32768 (s*64+b), N = 1536 (768 fwd | 768 bwd), K = 2000 (pad 2016)
// 128x128 tile, BK=32, 256 threads (4 waves, 2x2), mfma 16x16x32 bf16.
// =====================================================================
__global__ __launch_bounds__(256, 2)
void proj_gemm(const float* __restrict__ X,
               const float* __restrict__ Wf, const float* __restrict__ Wb,
               const float* __restrict__ bihf, const float* __restrict__ bihb,
               const float* __restrict__ bhhf, const float* __restrict__ bhhb,
               ushort* __restrict__ Gi)
{
    __shared__ __align__(16) ushort smem[16384];   // 32KB: staging 16KB, epilogue 32KB
    ushort* As = smem;          // [128][32] bf16 swizzled
    ushort* Bs = smem + 4096;   // [128][32] bf16 swizzled

    const int t    = threadIdx.x;
    const int lane = t & 63;
    const int w    = t >> 6;
    const int wr   = w >> 1, wc = w & 1;
    const int l15  = lane & 15, l4 = lane >> 4;
    const int tile_m0 = blockIdx.x * 128;
    const int tile_n0 = blockIdx.y * 128;

    const int st_row = t >> 1;
    const int st_c0  = (t & 1) * 16;

    f32x4_t acc[4][4];
    const f32x4_t vzero = {0.f, 0.f, 0.f, 0.f};
    #pragma unroll
    for (int i = 0; i < 4; ++i)
        #pragma unroll
        for (int j = 0; j < 4; ++j) acc[i][j] = vzero;

    const float* arow = X + (size_t)(tile_m0 + st_row) * V_IN;
    const int nrow = tile_n0 + st_row;
    const float* brow = (nrow < 768) ? (Wf + (size_t)nrow * V_IN)
                                     : (Wb + (size_t)(nrow - 768) * V_IN);

    for (int kt = 0; kt < 63; ++kt) {
        const int k0 = kt * 32;
        __syncthreads();
        #pragma unroll
        for (int i = 0; i < 4; ++i) {
            int c = st_c0 + i * 4;
            int k = k0 + c;
            float4 v = (k < V_IN) ? *(const float4*)(arow + k) : make_float4(0.f,0.f,0.f,0.f);
            float4 u = (k < V_IN) ? *(const float4*)(brow + k) : make_float4(0.f,0.f,0.f,0.f);
            ushort4 pv, pu;
            pv.x = f2b(v.x); pv.y = f2b(v.y); pv.z = f2b(v.z); pv.w = f2b(v.w);
            pu.x = f2b(u.x); pu.y = f2b(u.y); pu.z = f2b(u.z); pu.w = f2b(u.w);
            int slot = ((c >> 3) + (st_row >> 1)) & 3;
            int off  = st_row * 64 + slot * 16 + (c & 7) * 2;   // bytes
            *(ushort4*)((char*)As + off) = pv;
            *(ushort4*)((char*)Bs + off) = pu;
        }
        __syncthreads();
        bf16x8_t a[4], b[4];
        #pragma unroll
        for (int mi = 0; mi < 4; ++mi) {
            int r = wr * 64 + mi * 16 + l15;
            int slot = (l4 + (r >> 1)) & 3;
            a[mi] = *(bf16x8_t*)((char*)As + r * 64 + slot * 16);
        }
        #pragma unroll
        for (int ni = 0; ni < 4; ++ni) {
            int r = wc * 64 + ni * 16 + l15;
            int slot = (l4 + (r >> 1)) & 3;
            b[ni] = *(bf16x8_t*)((char*)Bs + r * 64 + slot * 16);
        }
        #pragma unroll
        for (int mi = 0; mi < 4; ++mi)
            #pragma unroll
            for (int ni = 0; ni < 4; ++ni)
                acc[mi][ni] = __builtin_amdgcn_mfma_f32_16x16x32_bf16(
                                  a[mi], b[ni], acc[mi][ni], 0, 0, 0);
    }

    // bias per output column (fold bih always; bhh for r,z gates)
    float bias[4];
    #pragma unroll
    for (int ni = 0; ni < 4; ++ni) {
        int ng = tile_n0 + wc * 64 + ni * 16 + l15;
        int dd = (ng >= 768);
        int nn = ng - dd * 768;
        float bsum = dd ? bihb[nn] : bihf[nn];
        if ((nn >> 8) < 2) bsum += dd ? bhhb[nn] : bhhf[nn];
        bias[ni] = bsum;
    }

    __syncthreads();   // staging LDS dead; reuse as Cs[128 n][128 m] bf16 swizzled
    #pragma unroll
    for (int mi = 0; mi < 4; ++mi) {
        int m0 = wr * 64 + mi * 16 + l4 * 4;
        #pragma unroll
        for (int ni = 0; ni < 4; ++ni) {
            int nl = wc * 64 + ni * 16 + l15;
            ushort4 pk;
            pk.x = f2b(acc[mi][ni][0] + bias[ni]);
            pk.y = f2b(acc[mi][ni][1] + bias[ni]);
            pk.z = f2b(acc[mi][ni][2] + bias[ni]);
            pk.w = f2b(acc[mi][ni][3] + bias[ni]);
            int off = nl * 256 + ((m0 * 2) ^ ((nl & 7) << 4));
            *(ushort4*)((char*)smem + off) = pk;
        }
    }
    __syncthreads();
    {
        const int nl = t & 127;
        const int sh = t >> 7;
        const int ng  = tile_n0 + nl;
        const int dd  = (ng >= 768);
        const int nn  = ng - dd * 768;
        const int tg  = nn >> 4;
        const int col = nn & 15;
        const int s   = (tile_m0 >> 6) + sh;
        size_t base = ((((size_t)s * 2 + dd) * 48 + tg) * 16 + col) * 64;
        #pragma unroll
        for (int i = 0; i < 8; ++i) {
            int off = nl * 256 + sh * 128 + ((i * 16) ^ ((nl & 7) << 4));
            bf16x8_t q = *(bf16x8_t*)((char*)smem + off);
            *(bf16x8_t*)(Gi + base + i * 8) = q;   // coalesced 16B stores
        }
    }
}

// =====================================================================
// K2: GRU scan. 8 WGs = {fwd,bwd} x 4 batch-groups of 16 rows; no
// cross-WG sync. 4 waves/WG; Whh bf16 register-resident (384 VGPR/wave).
// Wave w owns n-tiles {w*4+j} of each gate (12 tiles, 16x16x32 MFMA).
// =====================================================================
__global__ __launch_bounds__(256, 1)
void gru_scan(const ushort* __restrict__ Gi,
              const float* __restrict__ Whf, const float* __restrict__ Whb,
              const float* __restrict__ bhhf, const float* __restrict__ bhhb,
              float* __restrict__ Hout)
{
    __shared__ __align__(16) ushort hbuf[2][16 * 256];  // swizzled bf16 h, dbuf

    const int t    = threadIdx.x;
    const int lane = t & 63;
    const int w    = t >> 6;
    const int l15  = lane & 15, l4 = lane >> 4;
    const int d    = blockIdx.x & 1;
    const int g    = blockIdx.x >> 1;

    const float* Wh  = d ? Whb : Whf;
    const float* bhh = d ? bhhb : bhhf;

    // load register-resident weight fragments (bf16)
    bf16x8_t wf[12][8];
    #pragma unroll
    for (int gate = 0; gate < 3; ++gate)
        #pragma unroll
        for (int j = 0; j < 4; ++j) {
            int n = gate * 256 + (w * 4 + j) * 16 + l15;
            const float* wrow = Wh + (size_t)n * H_SZ;
            #pragma unroll
            for (int ks = 0; ks < 8; ++ks) {
                int k = ks * 32 + l4 * 8;
                float4 v0 = *(const float4*)(wrow + k);
                float4 v1 = *(const float4*)(wrow + k + 4);
                bf16x8_t f;
                f[0]=(short)f2b(v0.x); f[1]=(short)f2b(v0.y);
                f[2]=(short)f2b(v0.z); f[3]=(short)f2b(v0.w);
                f[4]=(short)f2b(v1.x); f[5]=(short)f2b(v1.y);
                f[6]=(short)f2b(v1.z); f[7]=(short)f2b(v1.w);
                wf[gate * 4 + j][ks] = f;
            }
        }
    float bhn[4];
    #pragma unroll
    for (int j = 0; j < 4; ++j)
        bhn[j] = bhh[512 + (w * 4 + j) * 16 + l15];

    // h0 = 0
    for (int i = t; i < 2 * 16 * 256 / 2; i += 256)
        ((unsigned int*)&hbuf[0][0])[i] = 0u;
    __syncthreads();

    const int b0  = l4 * 4;
    const int bg0 = g * 16 + b0;
    // Gi element index = s*98304 + off0 + (gate*16 + j)*1024
    const size_t off0 = (size_t)d * 49152 + (size_t)l15 * 64 + bg0 + (size_t)w * 4096;

    ushort4 giv[12];
    {
        int s0 = d ? 511 : 0;
        const ushort* gp = Gi + (size_t)s0 * 98304 + off0;
        #pragma unroll
        for (int gate = 0; gate < 3; ++gate)
            #pragma unroll
            for (int j = 0; j < 4; ++j)
                giv[gate * 4 + j] = *(const ushort4*)(gp + (gate * 16 + j) * 1024);
    }

    int p = 0;
    for (int step = 0; step < 512; ++step) {
        f32x4_t acc[12];
        const f32x4_t vzero = {0.f, 0.f, 0.f, 0.f};
        #pragma unroll
        for (int tt = 0; tt < 12; ++tt) acc[tt] = vzero;

        #pragma unroll
        for (int ks = 0; ks < 8; ++ks) {
            int coff = (ks * 64 + l4 * 16) ^ ((l15 & 7) << 4);
            bf16x8_t a = *(bf16x8_t*)((char*)&hbuf[p][0] + l15 * 512 + coff);
            #pragma unroll
            for (int tt = 0; tt < 12; ++tt)
                acc[tt] = __builtin_amdgcn_mfma_f32_16x16x32_bf16(
                              a, wf[tt][ks], acc[tt], 0, 0, 0);
        }

        // gates: this wave owns h columns (w*4+j)*16 + l15, rows b0..b0+3
        #pragma unroll
        for (int j = 0; j < 4; ++j) {
            int col = (w * 4 + j) * 16 + l15;
            #pragma unroll
            for (int reg = 0; reg < 4; ++reg) {
                int b = b0 + reg;
                float gir = b2f(u4get(giv[j], reg));          // incl. bih_r+bhh_r
                float giz = b2f(u4get(giv[4 + j], reg));      // incl. bih_z+bhh_z
                float gin = b2f(u4get(giv[8 + j], reg));      // incl. bih_n
                float r = __builtin_amdgcn_rcpf(1.0f + __expf(-(gir + acc[j][reg])));
                float z = __builtin_amdgcn_rcpf(1.0f + __expf(-(giz + acc[4 + j][reg])));
                float pre = gin + r * (acc[8 + j][reg] + bhn[j]);
                float e2  = __expf(2.0f * pre);
                float n   = 1.0f - 2.0f * __builtin_amdgcn_rcpf(e2 + 1.0f);
                int hoff = b * 512 + ((col * 2) ^ ((b & 7) << 4));
                float hold = b2f(*(ushort*)((char*)&hbuf[p][0] + hoff));
                float hnew = n + z * (hold - n);
                *(ushort*)((char*)&hbuf[p ^ 1][0] + hoff) = f2b(hnew);
            }
        }

        if (step + 1 < 512) {   // prefetch next step's gi (hidden under next MFMA)
            int sn = d ? (511 - (step + 1)) : (step + 1);
            const ushort* gp = Gi + (size_t)sn * 98304 + off0;
            #pragma unroll
            for (int gate = 0; gate < 3; ++gate)
                #pragma unroll
                for (int j = 0; j < 4; ++j)
                    giv[gate * 4 + j] = *(const ushort4*)(gp + (gate * 16 + j) * 1024);
        }
        __syncthreads();
        p ^= 1;
    }

    // final h -> fp32 Hout[d][64][256]
    for (int i = t; i < 16 * 256; i += 256) {
        int b = i >> 8, c = i & 255;
        int hoff = b * 512 + ((c * 2) ^ ((b & 7) << 4));
        float hv = b2f(*(ushort*)((char*)&hbuf[p][0] + hoff));
        Hout[((size_t)d * 64 + g * 16 + b) * 256 + c] = hv;
    }
}

// =====================================================================
// K3: VAE head. out = relu(u@Wmu.T+bmu) + eps * exp(0.5*relu(u@Wlv.T+blv))
// =====================================================================
__global__ __launch_bounds__(128)
void head_kernel(const float* __restrict__ Hbuf,
                 const float* __restrict__ Wmu, const float* __restrict__ bmu,
                 const float* __restrict__ Wlv, const float* __restrict__ blv,
                 const float* __restrict__ eps, float* __restrict__ out)
{
    __shared__ float u[512];
    __shared__ float mv[128];
    const int b = blockIdx.x;
    const int t = threadIdx.x;
    for (int i = t; i < 512; i += 128)
        u[i] = (i < 256) ? Hbuf[(size_t)b * 256 + i]
                         : Hbuf[(size_t)(64 + b) * 256 + (i - 256)];
    __syncthreads();
    const int z = t & 63;
    const bool ismu = t < 64;
    const float* wr = (ismu ? Wmu : Wlv) + (size_t)z * 512;
    float acc = ismu ? bmu[z] : blv[z];
    #pragma unroll 4
    for (int k = 0; k < 512; ++k) acc += u[k] * wr[k];
    acc = fmaxf(acc, 0.0f);
    mv[t] = acc;
    __syncthreads();
    if (t < 64) {
        float sd = __expf(0.5f * mv[64 + t]);
        out[(size_t)b * 64 + t] = mv[t] + eps[(size_t)b * 64 + t] * sd;
    }
}

// =====================================================================
extern "C" void kernel_launch(void* const* d_in, const int* in_sizes, int n_in,
                              void* d_out, int out_size, void* d_ws, size_t ws_size,
                              hipStream_t stream)
{
    const float* x    = (const float*)d_in[0];
    const float* Wihf = (const float*)d_in[1];
    const float* Whhf = (const float*)d_in[2];
    const float* bihf = (const float*)d_in[3];
    const float* bhhf = (const float*)d_in[4];
    const float* Wihb = (const float*)d_in[5];
    const float* Whhb = (const float*)d_in[6];
    const float* bihb = (const float*)d_in[7];
    const float* bhhb = (const float*)d_in[8];
    const float* Wmu  = (const float*)d_in[9];
    const float* bmu  = (const float*)d_in[10];
    const float* Wlv  = (const float*)d_in[11];
    const float* blv  = (const float*)d_in[12];
    const float* eps  = (const float*)d_in[13];

    // workspace: Gi bf16 [512][2][48][16][64] = 100663296 B, then Hout fp32 [2][64][256]
    ushort* Gi  = (ushort*)d_ws;
    float* Hbuf = (float*)((char*)d_ws + 100663296u);

    proj_gemm<<<dim3(256, 12), 256, 0, stream>>>(x, Wihf, Wihb, bihf, bihb,
                                                 bhhf, bhhb, Gi);
    gru_scan<<<8, 256, 0, stream>>>(Gi, Whhf, Whhb, bhhf, bhhb, Hbuf);
    head_kernel<<<64, 128, 0, stream>>>(Hbuf, Wmu, bmu, Wlv, blv, eps,
                                        (float*)d_out);
}

// Round 3
// 2753.681 us; speedup vs baseline: 1.3152x; 1.3152x over previous
//
#include <hip/hip_runtime.h>
#include <hip/hip_bf16.h>
#include <cstdint>

// Sizes (fixed by the problem)
#define S_LEN 512
#define B_SZ  64
#define V_IN  2000
#define H_SZ  256
#define Z_SZ  64

typedef __attribute__((ext_vector_type(4))) float  f32x4_t;
typedef __attribute__((ext_vector_type(8))) short  bf16x8_t;

// fp32 -> bf16 (RNE)
__device__ __forceinline__ ushort f2b(float f) {
    uint32_t u = __float_as_uint(f);
    u += 0x7FFFu + ((u >> 16) & 1u);
    return (ushort)(u >> 16);
}
__device__ __forceinline__ float b2f(ushort s) {
    return __uint_as_float(((uint32_t)s) << 16);
}
__device__ __forceinline__ ushort u4get(ushort4 v, int i) {
    return i == 0 ? v.x : i == 1 ? v.y : i == 2 ? v.z : v.w;
}

typedef __attribute__((address_space(3))) uint32_t lds_u32;
typedef const __attribute__((address_space(1))) uint32_t glb_u32;
__device__ __forceinline__ void gload16(const void* g, void* l) {
    // async global->LDS, 16B per lane; LDS dest = uniform base + lane*16
    __builtin_amdgcn_global_load_lds((glb_u32*)g, (lds_u32*)l, 16, 0, 0);
}

// =====================================================================
// K0a: cast X fp32 -> bf16 (65,536,000 elements, 8 per thread)
// =====================================================================
__global__ __launch_bounds__(256)
void cast_x(const float* __restrict__ X, ushort* __restrict__ Xb)
{
    size_t i = ((size_t)blockIdx.x * 256 + threadIdx.x) * 8;
    float4 v0 = *(const float4*)(X + i);
    float4 v1 = *(const float4*)(X + i + 4);
    bf16x8_t o;
    o[0] = (short)f2b(v0.x); o[1] = (short)f2b(v0.y);
    o[2] = (short)f2b(v0.z); o[3] = (short)f2b(v0.w);
    o[4] = (short)f2b(v1.x); o[5] = (short)f2b(v1.y);
    o[6] = (short)f2b(v1.z); o[7] = (short)f2b(v1.w);
    *(bf16x8_t*)(Xb + i) = o;
}

// =====================================================================
// K0b: pack Wih_f|Wih_b -> bf16 [1536][2016], zero-padded k in [2000,2016)
// =====================================================================
__global__ __launch_bounds__(256)
void pack_w(const float* __restrict__ Wf, const float* __restrict__ Wb,
            ushort* __restrict__ Wp)
{
    int idx = blockIdx.x * 256 + threadIdx.x;   // 8-elem chunk id
    int row = idx / 252;
    int k0  = (idx % 252) * 8;
    const float* src = (row < 768) ? (Wf + (size_t)row * 2000 + k0)
                                   : (Wb + (size_t)(row - 768) * 2000 + k0);
    bf16x8_t o;
    #pragma unroll
    for (int e = 0; e < 8; ++e) {
        float v = (k0 + e < 2000) ? src[e] : 0.0f;   // guarded read (OOB pad -> 0)
        o[e] = (short)f2b(v);
    }
    *(bf16x8_t*)(Wp + (size_t)row * 2016 + k0) = o;
}

// =====================================================================
// K1: projection GEMM (m97 structure).  Gi[s][d][tg][col][b] (bf16) =
//     x[s,b,:] @ Wih_d.T + bih_d (+ bhh_d folded for r,z gates)
// M=32768, N=1536, K=2000 (tail k>=2000: A junk x B zero = 0).
// 128x128 tile, BK=32, 4 waves (2x2), global_load_lds width 16.
// Linear LDS [128][32] bf16: 64B row stride -> b128 reads bank-balanced.
// =====================================================================
__global__ __launch_bounds__(256, 2)
void proj_gemm(const ushort* __restrict__ Xb, const ushort* __restrict__ Wp,
               const float* __restrict__ bihf, const float* __restrict__ bihb,
               const float* __restrict__ bhhf, const float* __restrict__ bhhb,
               ushort* __restrict__ Gi)
{
    __shared__ __align__(16) ushort smem[16384];   // 32KB: loop uses 16KB, epilogue all
    ushort* As = smem;          // [128][32] bf16 linear
    ushort* Bs = smem + 4096;   // [128][32] bf16 linear

    const int t    = threadIdx.x;
    const int lane = t & 63;
    const int w    = t >> 6;
    const int wr   = w >> 1, wc = w & 1;
    const int l15  = lane & 15, l4 = lane >> 4;

    // XCD-bijective swizzle: 3072 = 8 * 384; each XCD owns 32 consecutive
    // m-tiles (12 n-tiles each) -> X slab L2-resident, W streamed once/XCD.
    const int id = blockIdx.x;
    const int wg = (id & 7) * 384 + (id >> 3);
    const int m0 = (wg / 12) * 128;
    const int n0 = (wg % 12) * 128;

    f32x4_t acc[4][4];
    const f32x4_t vzero = {0.f, 0.f, 0.f, 0.f};
    #pragma unroll
    for (int i = 0; i < 4; ++i)
        #pragma unroll
        for (int j = 0; j < 4; ++j) acc[i][j] = vzero;

    // staging: chunk c = issue*256 + t; row = c>>2, kchunk = c&3 (8 bf16 = 16B)
    const int crow = t >> 2, ckc = t & 3;
    const ushort* a0 = Xb + (size_t)(m0 + crow) * 2000 + ckc * 8;
    const ushort* a1 = Xb + (size_t)(m0 + 64 + crow) * 2000 + ckc * 8;
    const ushort* b0 = Wp + (size_t)(n0 + crow) * 2016 + ckc * 8;
    const ushort* b1 = Wp + (size_t)(n0 + 64 + crow) * 2016 + ckc * 8;
    char* AsB = (char*)As;
    char* BsB = (char*)Bs;
    char* ldsA0 = AsB + (w * 64) * 16;           // + lane*16 by HW
    char* ldsA1 = AsB + (256 + w * 64) * 16;
    char* ldsB0 = BsB + (w * 64) * 16;
    char* ldsB1 = BsB + (256 + w * 64) * 16;

    for (int kt = 0; kt < 63; ++kt) {
        __syncthreads();                     // prior LDS reads done
        gload16(a0 + kt * 32, ldsA0);
        gload16(a1 + kt * 32, ldsA1);
        gload16(b0 + kt * 32, ldsB0);
        gload16(b1 + kt * 32, ldsB1);
        __syncthreads();                     // drains vmcnt (compiler-inserted)

        bf16x8_t af[4], bg[4];
        #pragma unroll
        for (int mi = 0; mi < 4; ++mi)
            af[mi] = *(bf16x8_t*)(AsB + (wr * 64 + mi * 16 + l15) * 64 + l4 * 16);
        #pragma unroll
        for (int ni = 0; ni < 4; ++ni)
            bg[ni] = *(bf16x8_t*)(BsB + (wc * 64 + ni * 16 + l15) * 64 + l4 * 16);
        #pragma unroll
        for (int mi = 0; mi < 4; ++mi)
            #pragma unroll
            for (int ni = 0; ni < 4; ++ni)
                acc[mi][ni] = __builtin_amdgcn_mfma_f32_16x16x32_bf16(
                                  af[mi], bg[ni], acc[mi][ni], 0, 0, 0);
    }

    // bias per output column (fold bih always; bhh for r,z gates)
    float bias[4];
    #pragma unroll
    for (int ni = 0; ni < 4; ++ni) {
        int ng = n0 + wc * 64 + ni * 16 + l15;
        int dd = (ng >= 768);
        int nn = ng - dd * 768;
        float bsum = dd ? bihb[nn] : bihf[nn];
        if ((nn >> 8) < 2) bsum += dd ? bhhb[nn] : bhhf[nn];
        bias[ni] = bsum;
    }

    __syncthreads();   // staging LDS dead; reuse as Cs[128 n][128 m] bf16 swizzled
    #pragma unroll
    for (int mi = 0; mi < 4; ++mi) {
        int cm0 = wr * 64 + mi * 16 + l4 * 4;
        #pragma unroll
        for (int ni = 0; ni < 4; ++ni) {
            int nl = wc * 64 + ni * 16 + l15;
            ushort4 pk;
            pk.x = f2b(acc[mi][ni][0] + bias[ni]);
            pk.y = f2b(acc[mi][ni][1] + bias[ni]);
            pk.z = f2b(acc[mi][ni][2] + bias[ni]);
            pk.w = f2b(acc[mi][ni][3] + bias[ni]);
            int off = nl * 256 + ((cm0 * 2) ^ ((nl & 7) << 4));
            *(ushort4*)((char*)smem + off) = pk;
        }
    }
    __syncthreads();
    {
        const int nl = t & 127;
        const int sh = t >> 7;
        const int ng  = n0 + nl;
        const int dd  = (ng >= 768);
        const int nn  = ng - dd * 768;
        const int tg  = nn >> 4;
        const int col = nn & 15;
        const int s   = (m0 >> 6) + sh;
        size_t base = ((((size_t)s * 2 + dd) * 48 + tg) * 16 + col) * 64;
        #pragma unroll
        for (int i = 0; i < 8; ++i) {
            int off = nl * 256 + sh * 128 + ((i * 16) ^ ((nl & 7) << 4));
            bf16x8_t q = *(bf16x8_t*)((char*)smem + off);
            *(bf16x8_t*)(Gi + base + i * 8) = q;   // coalesced 16B stores
        }
    }
}

// =====================================================================
// K2: GRU scan. 8 WGs = {fwd,bwd} x 4 batch-groups of 16 rows; no
// cross-WG sync. 16 waves/WG (1024 thr); wave w owns h-cols
// [w*16, w*16+16) for all 3 gates -> wf = 3x8 bf16x8 = 96 VGPR (no spill).
// MFMA-issue floor on 8 CUs ~= 400us.
// =====================================================================
__global__ __launch_bounds__(1024, 4)
void gru_scan(const ushort* __restrict__ Gi,
              const float* __restrict__ Whf, const float* __restrict__ Whb,
              const float* __restrict__ bhhf, const float* __restrict__ bhhb,
              float* __restrict__ Hout)
{
    __shared__ __align__(16) ushort hbuf[2][16 * 256];  // swizzled bf16 h, dbuf

    const int t    = threadIdx.x;
    const int lane = t & 63;
    const int w    = t >> 6;          // 0..15
    const int l15  = lane & 15, l4 = lane >> 4;
    const int d    = blockIdx.x & 1;
    const int g    = blockIdx.x >> 1;

    const float* Wh  = d ? Whb : Whf;
    const float* bhh = d ? bhhb : bhhf;

    // register-resident weights: 3 tiles (r,z,n) x 8 k-frags
    bf16x8_t wf[3][8];
    #pragma unroll
    for (int gate = 0; gate < 3; ++gate) {
        const float* wrow = Wh + (size_t)(gate * 256 + w * 16 + l15) * H_SZ;
        #pragma unroll
        for (int ks = 0; ks < 8; ++ks) {
            int k = ks * 32 + l4 * 8;
            float4 v0 = *(const float4*)(wrow + k);
            float4 v1 = *(const float4*)(wrow + k + 4);
            bf16x8_t f;
            f[0]=(short)f2b(v0.x); f[1]=(short)f2b(v0.y);
            f[2]=(short)f2b(v0.z); f[3]=(short)f2b(v0.w);
            f[4]=(short)f2b(v1.x); f[5]=(short)f2b(v1.y);
            f[6]=(short)f2b(v1.z); f[7]=(short)f2b(v1.w);
            wf[gate][ks] = f;
        }
    }
    const float bhn = bhh[512 + w * 16 + l15];

    // h0 = 0 (both buffers)
    for (int i = t; i < 16 * 256; i += 1024)
        ((unsigned int*)&hbuf[0][0])[i] = 0u;
    __syncthreads();

    const int b0 = l4 * 4;
    // Gi element index = s*98304 + off0 + gate*16384
    const size_t off0 = (size_t)d * 49152 + (size_t)w * 1024 + (size_t)l15 * 64
                      + g * 16 + b0;

    ushort4 giv[3];
    {
        int s0 = d ? 511 : 0;
        const ushort* gp = Gi + (size_t)s0 * 98304 + off0;
        #pragma unroll
        for (int gate = 0; gate < 3; ++gate)
            giv[gate] = *(const ushort4*)(gp + gate * 16384);
    }

    const int col = w * 16 + l15;
    float hold[4] = {0.f, 0.f, 0.f, 0.f};   // this lane's own h (rewritten each step)

    int p = 0;
    for (int step = 0; step < 512; ++step) {
        f32x4_t acc0 = {0.f,0.f,0.f,0.f}, acc1 = acc0, acc2 = acc0;

        #pragma unroll
        for (int ks = 0; ks < 8; ++ks) {
            int coff = (ks * 64 + l4 * 16) ^ ((l15 & 7) << 4);
            bf16x8_t a = *(bf16x8_t*)((char*)&hbuf[p][0] + l15 * 512 + coff);
            acc0 = __builtin_amdgcn_mfma_f32_16x16x32_bf16(a, wf[0][ks], acc0, 0, 0, 0);
            acc1 = __builtin_amdgcn_mfma_f32_16x16x32_bf16(a, wf[1][ks], acc1, 0, 0, 0);
            acc2 = __builtin_amdgcn_mfma_f32_16x16x32_bf16(a, wf[2][ks], acc2, 0, 0, 0);
        }

        #pragma unroll
        for (int reg = 0; reg < 4; ++reg) {
            int b = b0 + reg;
            float gir = b2f(u4get(giv[0], reg));          // incl. bih_r+bhh_r
            float giz = b2f(u4get(giv[1], reg));          // incl. bih_z+bhh_z
            float gin = b2f(u4get(giv[2], reg));          // incl. bih_n
            float r = __builtin_amdgcn_rcpf(1.0f + __expf(-(gir + acc0[reg])));
            float z = __builtin_amdgcn_rcpf(1.0f + __expf(-(giz + acc1[reg])));
            float pre = gin + r * (acc2[reg] + bhn);
            float e2  = __expf(2.0f * pre);
            float n   = 1.0f - 2.0f * __builtin_amdgcn_rcpf(e2 + 1.0f);
            float hnew = n + z * (hold[reg] - n);
            hold[reg] = hnew;
            int hoff = b * 512 + ((col * 2) ^ ((b & 7) << 4));
            *(ushort*)((char*)&hbuf[p ^ 1][0] + hoff) = f2b(hnew);
        }

        if (step + 1 < 512) {   // prefetch next step's gi (hidden under next MFMA)
            int sn = d ? (511 - (step + 1)) : (step + 1);
            const ushort* gp = Gi + (size_t)sn * 98304 + off0;
            #pragma unroll
            for (int gate = 0; gate < 3; ++gate)
                giv[gate] = *(const ushort4*)(gp + gate * 16384);
        }
        __syncthreads();
        p ^= 1;
    }

    // final h -> fp32 Hout[d][64][256]
    for (int i = t; i < 16 * 256; i += 1024) {
        int b = i >> 8, c = i & 255;
        int hoff = b * 512 + ((c * 2) ^ ((b & 7) << 4));
        float hv = b2f(*(ushort*)((char*)&hbuf[p][0] + hoff));
        Hout[((size_t)d * 64 + g * 16 + b) * 256 + c] = hv;
    }
}

// =====================================================================
// K3: VAE head. out = relu(u@Wmu.T+bmu) + eps * exp(0.5*relu(u@Wlv.T+blv))
// =====================================================================
__global__ __launch_bounds__(128)
void head_kernel(const float* __restrict__ Hbuf,
                 const float* __restrict__ Wmu, const float* __restrict__ bmu,
                 const float* __restrict__ Wlv, const float* __restrict__ blv,
                 const float* __restrict__ eps, float* __restrict__ out)
{
    __shared__ float u[512];
    __shared__ float mv[128];
    const int b = blockIdx.x;
    const int t = threadIdx.x;
    for (int i = t; i < 512; i += 128)
        u[i] = (i < 256) ? Hbuf[(size_t)b * 256 + i]
                         : Hbuf[(size_t)(64 + b) * 256 + (i - 256)];
    __syncthreads();
    const int z = t & 63;
    const bool ismu = t < 64;
    const float* wr = (ismu ? Wmu : Wlv) + (size_t)z * 512;
    float acc = ismu ? bmu[z] : blv[z];
    #pragma unroll 4
    for (int k = 0; k < 512; ++k) acc += u[k] * wr[k];
    acc = fmaxf(acc, 0.0f);
    mv[t] = acc;
    __syncthreads();
    if (t < 64) {
        float sd = __expf(0.5f * mv[64 + t]);
        out[(size_t)b * 64 + t] = mv[t] + eps[(size_t)b * 64 + t] * sd;
    }
}

// =====================================================================
extern "C" void kernel_launch(void* const* d_in, const int* in_sizes, int n_in,
                              void* d_out, int out_size, void* d_ws, size_t ws_size,
                              hipStream_t stream)
{
    const float* x    = (const float*)d_in[0];
    const float* Wihf = (const float*)d_in[1];
    const float* Whhf = (const float*)d_in[2];
    const float* bihf = (const float*)d_in[3];
    const float* bhhf = (const float*)d_in[4];
    const float* Wihb = (const float*)d_in[5];
    const float* Whhb = (const float*)d_in[6];
    const float* bihb = (const float*)d_in[7];
    const float* bhhb = (const float*)d_in[8];
    const float* Wmu  = (const float*)d_in[9];
    const float* bmu  = (const float*)d_in[10];
    const float* Wlv  = (const float*)d_in[11];
    const float* blv  = (const float*)d_in[12];
    const float* eps  = (const float*)d_in[13];

    // workspace layout (bytes):
    //   Gi  bf16 [512][2][48][16][64]             @ 0          (100,663,296)
    //   Xb  bf16 [32768][2000] (+256 slack)       @ 100663296  (131,072,256)
    //   Wp  bf16 [1536][2016] zero-padded         @ 231735552  (  6,193,152)
    //   Hbuf fp32 [2][64][256]                    @ 237928704  (    131,072)
    ushort* Gi   = (ushort*)d_ws;
    ushort* Xb   = (ushort*)((char*)d_ws + 100663296u);
    ushort* Wp   = (ushort*)((char*)d_ws + 231735552u);
    float*  Hbuf = (float*)((char*)d_ws + 237928704u);

    cast_x<<<32000, 256, 0, stream>>>(x, Xb);
    pack_w<<<1512, 256, 0, stream>>>(Wihf, Wihb, Wp);
    proj_gemm<<<3072, 256, 0, stream>>>(Xb, Wp, bihf, bihb, bhhf, bhhb, Gi);
    gru_scan<<<8, 1024, 0, stream>>>(Gi, Whhf, Whhb, bhhf, bhhb, Hbuf);
    head_kernel<<<64, 128, 0, stream>>>(Hbuf, Wmu, bmu, Wlv, blv, eps,
                                        (float*)d_out);
}